// Round 9
// baseline (246.029 us; speedup 1.0000x reference)
//
#include <hip/hip_runtime.h>
#include <hip/hip_bf16.h>

// Round 9: linearity refactor + MFMA pos-L1.
//   combine: frags ALL weights; computes Wsrc'=W_src@aW1, Wdst'=W_dst@aW1 via MFMA;
//            pos1 frag set folds pW1+pb1 (input [d0,d1,d2,1]).
//   node_in: outputs v(bf16), B_src=x1@Wsrc' (bf16), B_dst=x1@Wdst'+ab1 (f32).
//   edge:    attn1 = relu(mfma(delta_frag) + Bd - Bs); zero in-loop small-LDS reads.
// frag sets: 0-7 pW2 | 8-15 aW1 | 16-23 aW2 | 24-27 pos1 | 28-35 W_in |
//            36-43 W_lin | 44-51 Wsrc' | 52-59 Wdst' | 60-67 W_out

using bf16x8 = __attribute__((ext_vector_type(8))) short;
using f32x4  = __attribute__((ext_vector_type(4))) float;
using u16x4  = __attribute__((ext_vector_type(4))) unsigned short;

__device__ __forceinline__ uint32_t cvtpk(float a, float b) {
  uint32_t d;
  asm("v_cvt_pk_bf16_f32 %0, %1, %2" : "=v"(d) : "v"(a), "v"(b));
  return d;
}
__device__ __forceinline__ float bf2f(unsigned short s) {
  union { uint32_t u; float f; } v; v.u = ((uint32_t)s) << 16;
  return v.f;
}
__device__ __forceinline__ float bf2fs(short s) { return bf2f((unsigned short)s); }
__device__ __forceinline__ bf16x8 mk8(uint32_t a, uint32_t b, uint32_t c, uint32_t d) {
  union { uint4 q; bf16x8 v; } u;
  u.q.x = a; u.q.y = b; u.q.z = c; u.q.w = d;
  return u.v;
}
__device__ __forceinline__ f32x4 mfma16(bf16x8 a, bf16x8 b, f32x4 c) {
  return __builtin_amdgcn_mfma_f32_16x16x32_bf16(a, b, c, 0, 0, 0);
}
#define LGKM0 asm volatile("s_waitcnt lgkmcnt(0)" ::: "memory")

// ================= combine: all weight frags + 2 MFMA weight-matmuls =================
__global__ __launch_bounds__(256) void combine_kernel(
    const float* __restrict__ pW1, const float* __restrict__ pb1,
    const float* __restrict__ pW2, const float* __restrict__ aW1,
    const float* __restrict__ aW2,
    const float* __restrict__ W_in, const float* __restrict__ W_lin,
    const float* __restrict__ W_src, const float* __restrict__ W_dst,
    const float* __restrict__ W_out, uint4* __restrict__ frag) {
  const int tid = threadIdx.x;
  if (blockIdx.x == 0) {
    // plain frags: sets 0-23 (pW2,aW1,aW2), 28-43 (W_in,W_lin), 60-67 (W_out)
#pragma unroll
    for (int it = 0; it < 12; ++it) {
      const int li = it * 256 + tid;
      const int sIdx = li >> 6, l2 = li & 63;
      const float* W; int set;
      if      (sIdx <  8) { W = pW2;   set = sIdx; }
      else if (sIdx < 16) { W = aW1;   set = sIdx; }
      else if (sIdx < 24) { W = aW2;   set = sIdx; }
      else if (sIdx < 32) { W = W_in;  set = sIdx + 4; }
      else if (sIdx < 40) { W = W_lin; set = sIdx + 4; }
      else                { W = W_out; set = sIdx + 20; }
      const int fl = sIdx & 7;
      const int half = (fl >> 2) & 1, t = fl & 3;
      const int lo = l2 & 15, hi = l2 >> 4;
      const int c = t * 16 + lo;
      const int k = 32 * half + hi * 8;
      uint4 q;
      q.x = cvtpk(W[(k + 0) * 64 + c], W[(k + 1) * 64 + c]);
      q.y = cvtpk(W[(k + 2) * 64 + c], W[(k + 3) * 64 + c]);
      q.z = cvtpk(W[(k + 4) * 64 + c], W[(k + 5) * 64 + c]);
      q.w = cvtpk(W[(k + 6) * 64 + c], W[(k + 7) * 64 + c]);
      frag[set * 64 + l2] = q;
    }
    return;
  }
  // block 1: pos1 sets 24-27; Wsrc@aW1 -> 44-51; Wdst@aW1 -> 52-59
  __shared__ uint32_t sA[8][64][4];   // aW1 frags
  __shared__ float    sP[64 * 68];    // product matrix, padded stride
  for (int it = tid; it < 8 * 64; it += 256) {
    const int fl = it >> 6, l2 = it & 63;
    const int half = (fl >> 2) & 1, t = fl & 3;
    const int lo = l2 & 15, hi = l2 >> 4;
    const int c = t * 16 + lo;
    const int k = 32 * half + hi * 8;
    uint4 q;
    q.x = cvtpk(aW1[(k + 0) * 64 + c], aW1[(k + 1) * 64 + c]);
    q.y = cvtpk(aW1[(k + 2) * 64 + c], aW1[(k + 3) * 64 + c]);
    q.z = cvtpk(aW1[(k + 4) * 64 + c], aW1[(k + 5) * 64 + c]);
    q.w = cvtpk(aW1[(k + 6) * 64 + c], aW1[(k + 7) * 64 + c]);
    *(uint4*)&sA[fl][l2][0] = q;
  }
  {
    // pos1 combo frag: A[c][k] with rows 0-2 = pW1, row 3 = pb1, rest 0 (half 0 only)
    const int t = tid >> 6, l2 = tid & 63;
    const int lo = l2 & 15, hi = l2 >> 4;
    const int c = t * 16 + lo;
    uint4 q = make_uint4(0, 0, 0, 0);
    if (hi == 0) {
      q.x = cvtpk(pW1[c], pW1[64 + c]);
      q.y = cvtpk(pW1[128 + c], pb1[c]);
    }
    frag[(24 + t) * 64 + l2] = q;
  }
  __syncthreads();
  const int w = tid >> 6, lane = tid & 63;
  const int lo = lane & 15, hi = lane >> 4;
  for (int mm = 0; mm < 2; ++mm) {
    const float* Wm = mm ? W_dst : W_src;
    const int row = w * 16 + lo;            // 4 waves cover 64 rows
    bf16x8 bfr[2];
#pragma unroll
    for (int half = 0; half < 2; ++half) {
      const f32x4 X0 = *(const f32x4*)&Wm[row * 64 + 32 * half + hi * 8];
      const f32x4 X1 = *(const f32x4*)&Wm[row * 64 + 32 * half + hi * 8 + 4];
      bfr[half] = mk8(cvtpk(X0[0], X0[1]), cvtpk(X0[2], X0[3]),
                      cvtpk(X1[0], X1[1]), cvtpk(X1[2], X1[3]));
    }
#pragma unroll
    for (int t = 0; t < 4; ++t) {
      f32x4 acc = {0.f, 0.f, 0.f, 0.f};
      acc = mfma16(*(const bf16x8*)&sA[t][lane][0],     bfr[0], acc);
      acc = mfma16(*(const bf16x8*)&sA[4 + t][lane][0], bfr[1], acc);
      *(f32x4*)&sP[row * 68 + t * 16 + hi * 4] = acc;
    }
    __syncthreads();
    for (int it = tid; it < 8 * 64; it += 256) {
      const int fl = it >> 6, l2 = it & 63;
      const int half = (fl >> 2) & 1, t = fl & 3;
      const int lo2 = l2 & 15, hi2 = l2 >> 4;
      const int c = t * 16 + lo2;
      const int k0 = 32 * half + hi2 * 8;
      uint4 q;
      q.x = cvtpk(sP[(k0 + 0) * 68 + c], sP[(k0 + 1) * 68 + c]);
      q.y = cvtpk(sP[(k0 + 2) * 68 + c], sP[(k0 + 3) * 68 + c]);
      q.z = cvtpk(sP[(k0 + 4) * 68 + c], sP[(k0 + 5) * 68 + c]);
      q.w = cvtpk(sP[(k0 + 6) * 68 + c], sP[(k0 + 7) * 68 + c]);
      frag[(mm ? 52 : 44) * 64 + it] = q;
    }
    __syncthreads();
  }
}

// ================= fused prep: hist + node_in =================
__global__ __launch_bounds__(256, 3) void fused_prep_kernel(
    const int* __restrict__ eidx, int* __restrict__ cursor, int E,
    const float* __restrict__ x, const float* __restrict__ b_in,
    const float* __restrict__ ab1,
    const uint4* __restrict__ frag,
    unsigned short* __restrict__ vbf, unsigned short* __restrict__ bsrc,
    float* __restrict__ bdst, int N, int HB) {
  __shared__ uint32_t sWfrag[32][64][4];
  __shared__ float    sBias[64];
  __shared__ float    sBias2[64];
  __shared__ float    sXp[4][16 * 68];

  const int tid = threadIdx.x;
  if ((int)blockIdx.x < HB) {
    const int base = ((int)blockIdx.x * 256 + tid) * 4;
    if (base + 3 < E) {
      const int4 d = *(const int4*)(eidx + E + base);
      atomicAdd(&cursor[d.x], 1);
      atomicAdd(&cursor[d.y], 1);
      atomicAdd(&cursor[d.z], 1);
      atomicAdd(&cursor[d.w], 1);
    } else {
      for (int j = base; j < E; ++j) atomicAdd(&cursor[eidx[E + j]], 1);
    }
    return;
  }
  const int bid = blockIdx.x - HB;
  const int nbn = gridDim.x - HB;

  {
    uint4* sW4 = (uint4*)sWfrag;
    const uint4* srcf = frag + 28 * 64;
    for (int i = tid; i < 32 * 64; i += 256) sW4[i] = srcf[i];
  }
  if (tid < 64) { sBias[tid] = b_in[tid]; sBias2[tid] = ab1[tid]; }
  __syncthreads();

  const int w  = tid >> 6, l = tid & 63;
  const int lo = l & 15,  hi = l >> 4;
  float*   xb     = &sXp[w][0];
  uint8_t* trbase = (uint8_t*)xb;
  const uint32_t swz = (uint32_t)((lo & 7) << 4);
  const int rr = l >> 5, cc = l & 31;

#define WF(m, half, t) (*(const bf16x8*)&sWfrag[(m) * 8 + (half) * 4 + (t)][l][0])

  const int ntiles = (N + 15) >> 4;
  for (int tile = bid * 4 + w; tile < ntiles; tile += nbn * 4) {
    const int row = tile * 16 + lo;
    const int rowc = row < N ? row : (N - 1);
    bf16x8 xf[2];
#pragma unroll
    for (int half = 0; half < 2; ++half) {
      const int base = 32 * half + hi * 8;
      const f32x4 X0 = *(const f32x4*)&x[(size_t)rowc * 64 + base];
      const f32x4 X1 = *(const f32x4*)&x[(size_t)rowc * 64 + base + 4];
      xf[half] = mk8(cvtpk(X0[0], X0[1]), cvtpk(X0[2], X0[3]),
                     cvtpk(X1[0], X1[1]), cvtpk(X1[2], X1[3]));
    }
    f32x4 x1[4];
#pragma unroll
    for (int t = 0; t < 4; ++t) {
      f32x4 acc = *(const f32x4*)&sBias[t * 16 + hi * 4];
      acc = mfma16(WF(0, 0, t), xf[0], acc);
      acc = mfma16(WF(0, 1, t), xf[1], acc);
#pragma unroll
      for (int r = 0; r < 4; ++r) x1[t][r] = fmaxf(acc[r], 0.f);
    }
    LGKM0;
#pragma unroll
    for (int t = 0; t < 4; ++t) {
      uint2 p; p.x = cvtpk(x1[t][0], x1[t][1]); p.y = cvtpk(x1[t][2], x1[t][3]);
      *(uint2*)(trbase + lo * 128 + (((uint32_t)(t * 32 + hi * 8)) ^ swz)) = p;
    }
    LGKM0;
    const bf16x8 x1f0 = *(const bf16x8*)(trbase + lo * 128 + (((uint32_t)(hi * 16)) ^ swz));
    const bf16x8 x1f1 = *(const bf16x8*)(trbase + lo * 128 + (((uint32_t)(64 + hi * 16)) ^ swz));

#pragma unroll
    for (int m = 1; m <= 3; ++m) {
      f32x4 res[4];
#pragma unroll
      for (int t = 0; t < 4; ++t) {
        f32x4 acc;
        if (m == 3) acc = *(const f32x4*)&sBias2[t * 16 + hi * 4];
        else        acc = f32x4{0.f, 0.f, 0.f, 0.f};
        acc = mfma16(WF(m, 0, t), x1f0, acc);
        acc = mfma16(WF(m, 1, t), x1f1, acc);
        res[t] = acc;
      }
#pragma unroll
      for (int t = 0; t < 4; ++t)
        *(f32x4*)&xb[lo * 68 + t * 16 + hi * 4] = res[t];
      LGKM0;
      if (m == 3) {
#pragma unroll
        for (int ee = 0; ee < 16; ++ee) {
          const int r2 = tile * 16 + ee;
          if (r2 < N) bdst[(size_t)r2 * 64 + l] = xb[ee * 68 + l];
        }
      } else {
        unsigned short* outp = (m == 1) ? vbf : bsrc;
#pragma unroll
        for (int ee2 = 0; ee2 < 16; ee2 += 2) {
          const int er = ee2 + rr;
          const int r2 = tile * 16 + er;
          const uint32_t pk = cvtpk(xb[er * 68 + 2 * cc], xb[er * 68 + 2 * cc + 1]);
          if (r2 < N) *(uint32_t*)&outp[(size_t)r2 * 64 + 2 * cc] = pk;
        }
      }
      LGKM0;
    }
  }
#undef WF
}

// ================= scan (2 dispatches) =================
#define SCAN_CH 1024
__global__ __launch_bounds__(256) void scan_blocksum(
    const int* __restrict__ cursor, int* __restrict__ bsum, int N) {
  __shared__ int red[4];
  const int base = blockIdx.x * SCAN_CH + threadIdx.x * 4;
  int s = 0;
#pragma unroll
  for (int j = 0; j < 4; ++j) { const int i = base + j; if (i < N) s += cursor[i]; }
  for (int off = 1; off < 64; off <<= 1) s += __shfl_xor(s, off);
  if ((threadIdx.x & 63) == 0) red[threadIdx.x >> 6] = s;
  __syncthreads();
  if (threadIdx.x == 0) bsum[blockIdx.x] = red[0] + red[1] + red[2] + red[3];
}

__global__ __launch_bounds__(256) void scan_final(
    int* __restrict__ cursor, const int* __restrict__ bsum, int N) {
  __shared__ int woff[4];
  __shared__ int sBoff;
  const int tid = threadIdx.x;
  const int base = blockIdx.x * SCAN_CH + tid * 4;
  int xv[4]; int s = 0;
#pragma unroll
  for (int j = 0; j < 4; ++j) { const int i = base + j; xv[j] = (i < N) ? cursor[i] : 0; s += xv[j]; }
  int v = s;
  const int lane = tid & 63, wid = tid >> 6;
  for (int off = 1; off < 64; off <<= 1) {
    const int u = __shfl_up(v, off);
    if (lane >= off) v += u;
  }
  if (lane == 63) woff[wid] = v;
  if (tid < 64) {   // wave 0 also computes this block's bsum prefix (nb <= 64)
    int val = (tid < (int)blockIdx.x) ? bsum[tid] : 0;
    for (int off = 1; off < 64; off <<= 1) val += __shfl_xor(val, off);
    if (tid == 0) sBoff = val;
  }
  __syncthreads();
  int waveoff = 0;
#pragma unroll
  for (int k = 0; k < 4; ++k) waveoff += (k < wid) ? woff[k] : 0;
  int ex = sBoff + waveoff + (v - s);
#pragma unroll
  for (int j = 0; j < 4; ++j) {
    const int i = base + j;
    if (i < N) { cursor[i] = ex; ex += xv[j]; }
  }
}

__global__ __launch_bounds__(256) void scatter_kernel(
    const int* __restrict__ eidx, int* __restrict__ cursor,
    uint32_t* __restrict__ sorted, int E) {
  const int e = blockIdx.x * 256 + threadIdx.x;
  if (e < E) {
    const int s = eidx[e];
    const int d = eidx[E + e];
    const int slot = atomicAdd(&cursor[d], 1);
    sorted[slot] = ((uint32_t)d << 16) | (uint32_t)s;
  }
}

// ================= edge kernel =================
__global__ __launch_bounds__(512, 4) void edge_mfma_kernel(
    const float* __restrict__ pos,
    const unsigned short* __restrict__ vbf,
    const unsigned short* __restrict__ bsrc,
    const float* __restrict__ bdst,
    const float* __restrict__ pb2, const float* __restrict__ ab2,
    const uint4* __restrict__ frag,
    const uint32_t* __restrict__ sorted,
    float* __restrict__ num, float* __restrict__ den, int E) {
  __shared__ uint32_t sWfrag[28][64][4];   // pW2(0-7), aW1(8-15), aW2(16-23), pos1(24-27)
  __shared__ float    sXp[8][16 * 68];
  __shared__ int      sDst[8][16];

  const int tid = threadIdx.x;
  {
    uint4* sW4 = (uint4*)sWfrag;
    for (int i = tid; i < 28 * 64; i += 512) sW4[i] = frag[i];
  }
  __syncthreads();

  const int w  = tid >> 6, l = tid & 63;
  const int lo = l & 15,  hi = l >> 4;
  float*   xb     = &sXp[w][0];
  uint8_t* trbase = (uint8_t*)xb;
  const uint32_t swz = (uint32_t)((lo & 7) << 4);

#define WF(m, half, t) (*(const bf16x8*)&sWfrag[(m) * 8 + (half) * 4 + (t)][l][0])

  // hoisted loop-invariants
  bf16x8 posA[4];
#pragma unroll
  for (int t = 0; t < 4; ++t) posA[t] = *(const bf16x8*)&sWfrag[24 + t][l][0];
  f32x4 pb2i[4], ab2i[4];
#pragma unroll
  for (int t = 0; t < 4; ++t) {
    pb2i[t] = *(const f32x4*)&pb2[t * 16 + hi * 4];
    ab2i[t] = *(const f32x4*)&ab2[t * 16 + hi * 4];
  }

  const int ntiles = (E + 15) >> 4;
  const int stride = gridDim.x * 8;

  int cs = 0, cd = 0; float c0 = 0.f, c1 = 0.f, c2 = 0.f;
  {
    const int t0 = blockIdx.x * 8 + w;
    if (t0 < ntiles) {
      const int ee = t0 * 16 + lo;
      const int ec = ee < E ? ee : (E - 1);
      const uint32_t se = sorted[ec];
      cs = (int)(se & 0xFFFFu); cd = (int)(se >> 16);
      c0 = pos[cd * 3 + 0] - pos[cs * 3 + 0];
      c1 = pos[cd * 3 + 1] - pos[cs * 3 + 1];
      c2 = pos[cd * 3 + 2] - pos[cs * 3 + 2];
    }
  }

  for (int tile = blockIdx.x * 8 + w; tile < ntiles; tile += stride) {
    const int src = cs, dst = cd;
    const float d0 = c0, d1 = c1, d2 = c2;
    const size_t db = (size_t)dst * 64, sb = (size_t)src * 64;

    // gathers (C-layout quads): Bd f32 (broadcast per run), Bs/V bf16 random
    f32x4 Bd[4]; u16x4 Bs[4]; u16x4 V[4];
#pragma unroll
    for (int t = 0; t < 4; ++t) {
      Bd[t] = *(const f32x4*)&bdst[db + t * 16 + hi * 4];
      Bs[t] = *(const u16x4*)&bsrc[sb + t * 16 + hi * 4];
      V[t]  = *(const u16x4*)&vbf [sb + t * 16 + hi * 4];
    }

    // prefetch next tile
    const int nt = tile + stride;
    if (nt < ntiles) {
      const int ee = nt * 16 + lo;
      const int ec = ee < E ? ee : (E - 1);
      const uint32_t se = sorted[ec];
      cs = (int)(se & 0xFFFFu); cd = (int)(se >> 16);
      c0 = pos[cd * 3 + 0] - pos[cs * 3 + 0];
      c1 = pos[cd * 3 + 1] - pos[cs * 3 + 1];
      c2 = pos[cd * 3 + 2] - pos[cs * 3 + 2];
    }

    if (hi == 0) sDst[w][lo] = dst;

    // ---- pos layer 1 via MFMA: in = [d0,d1,d2,1] (K=4 of 32, hi==0 lanes) ----
    const uint32_t p0 = cvtpk(d0, d1), p1 = cvtpk(d2, 1.0f);
    const bf16x8 inB = mk8(hi == 0 ? p0 : 0u, hi == 0 ? p1 : 0u, 0u, 0u);
    f32x4 hC[4];
#pragma unroll
    for (int t = 0; t < 4; ++t) {
      f32x4 acc = {0.f, 0.f, 0.f, 0.f};
      acc = mfma16(posA[t], inB, acc);
#pragma unroll
      for (int r = 0; r < 4; ++r) hC[t][r] = fmaxf(acc[r], 0.f);
    }
    // transpose h -> region A [0,2048)
    LGKM0;   // prior tile's epilogue reads done
#pragma unroll
    for (int t = 0; t < 4; ++t) {
      uint2 p; p.x = cvtpk(hC[t][0], hC[t][1]); p.y = cvtpk(hC[t][2], hC[t][3]);
      *(uint2*)(trbase + lo * 128 + (((uint32_t)(t * 32 + hi * 8)) ^ swz)) = p;
    }
    LGKM0;
    const bf16x8 hf0 = *(const bf16x8*)(trbase + lo * 128 + (((uint32_t)(hi * 16)) ^ swz));
    const bf16x8 hf1 = *(const bf16x8*)(trbase + lo * 128 + (((uint32_t)(64 + hi * 16)) ^ swz));

    // ---- pos layer 2 ----
    f32x4 dl[4];
#pragma unroll
    for (int t = 0; t < 4; ++t) {
      f32x4 acc = pb2i[t];
      acc = mfma16(WF(0, 0, t), hf0, acc);
      acc = mfma16(WF(0, 1, t), hf1, acc);
#pragma unroll
      for (int r = 0; r < 4; ++r) dl[t][r] = fmaxf(acc[r], 0.f);
    }
    // transpose delta -> region B [2048,4096)
#pragma unroll
    for (int t = 0; t < 4; ++t) {
      uint2 p; p.x = cvtpk(dl[t][0], dl[t][1]); p.y = cvtpk(dl[t][2], dl[t][3]);
      *(uint2*)(trbase + 2048 + lo * 128 + (((uint32_t)(t * 32 + hi * 8)) ^ swz)) = p;
    }
    LGKM0;
    const bf16x8 dfr0 = *(const bf16x8*)(trbase + 2048 + lo * 128 + (((uint32_t)(hi * 16)) ^ swz));
    const bf16x8 dfr1 = *(const bf16x8*)(trbase + 2048 + lo * 128 + (((uint32_t)(64 + hi * 16)) ^ swz));

    // ---- attn layer 1: relu(delta@aW1 + Bd - Bs) ----
    f32x4 ga[4];
#pragma unroll
    for (int t = 0; t < 4; ++t) {
      f32x4 acc = {0.f, 0.f, 0.f, 0.f};
      acc = mfma16(WF(1, 0, t), dfr0, acc);
      acc = mfma16(WF(1, 1, t), dfr1, acc);
#pragma unroll
      for (int r = 0; r < 4; ++r)
        ga[t][r] = fmaxf(acc[r] + Bd[t][r] - bf2f(Bs[t][r]), 0.f);
    }
    // transpose ga -> region A [0,2048) (h consumed)
#pragma unroll
    for (int t = 0; t < 4; ++t) {
      uint2 p; p.x = cvtpk(ga[t][0], ga[t][1]); p.y = cvtpk(ga[t][2], ga[t][3]);
      *(uint2*)(trbase + lo * 128 + (((uint32_t)(t * 32 + hi * 8)) ^ swz)) = p;
    }
    LGKM0;
    const bf16x8 gf0 = *(const bf16x8*)(trbase + lo * 128 + (((uint32_t)(hi * 16)) ^ swz));
    const bf16x8 gf1 = *(const bf16x8*)(trbase + lo * 128 + (((uint32_t)(64 + hi * 16)) ^ swz));

    // ---- attn layer 2 -> exp -> nv ----
    f32x4 exv[4];
#pragma unroll
    for (int t = 0; t < 4; ++t) {
      f32x4 acc = ab2i[t];
      acc = mfma16(WF(2, 0, t), gf0, acc);
      acc = mfma16(WF(2, 1, t), gf1, acc);
      f32x4 nv;
#pragma unroll
      for (int r = 0; r < 4; ++r) {
        const float ex = __expf(fmaxf(acc[r], 0.f));
        exv[t][r] = ex;
        nv[r] = ex * (bf2f(V[t][r]) + dl[t][r]);
      }
      *(f32x4*)&xb[lo * 68 + t * 16 + hi * 4] = nv;
    }
    LGKM0;
    const int tbase = tile * 16;
    {
      int run_d = __builtin_amdgcn_readfirstlane(sDst[w][0]);
      float acc = 0.f;
#pragma unroll
      for (int ee = 0; ee < 16; ++ee) {
        if (tbase + ee < E) {
          const int de = __builtin_amdgcn_readfirstlane(sDst[w][ee]);
          const float nv = xb[ee * 68 + l];
          if (de != run_d) {
            atomicAdd(&num[(size_t)run_d * 64 + l], acc);
            run_d = de; acc = 0.f;
          }
          acc += nv;
        }
      }
      atomicAdd(&num[(size_t)run_d * 64 + l], acc);
    }
#pragma unroll
    for (int t = 0; t < 4; ++t)
      *(f32x4*)&xb[lo * 68 + t * 16 + hi * 4] = exv[t];
    LGKM0;
    {
      int run_d = __builtin_amdgcn_readfirstlane(sDst[w][0]);
      float acc = 0.f;
#pragma unroll
      for (int ee = 0; ee < 16; ++ee) {
        if (tbase + ee < E) {
          const int de = __builtin_amdgcn_readfirstlane(sDst[w][ee]);
          const float dv = xb[ee * 68 + l];
          if (de != run_d) {
            atomicAdd(&den[(size_t)run_d * 64 + l], acc);
            run_d = de; acc = 0.f;
          }
          acc += dv;
        }
      }
      atomicAdd(&den[(size_t)run_d * 64 + l], acc);
    }
  }
#undef WF
}

// ================= node_out (MFMA) =================
__global__ __launch_bounds__(512, 4) void node_out_mfma(
    const float* __restrict__ num, const float* __restrict__ den,
    const uint4* __restrict__ frag, const float* __restrict__ b_out,
    float* __restrict__ out, int N) {
  __shared__ uint32_t sWfrag[8][64][4];
  __shared__ float    sBias[64];
  __shared__ float    sXp[8][16 * 68];

  const int tid = threadIdx.x;
  {
    uint4* sW4 = (uint4*)sWfrag;
    const uint4* srcf = frag + 60 * 64;
    for (int i = tid; i < 8 * 64; i += 512) sW4[i] = srcf[i];
  }
  if (tid < 64) sBias[tid] = b_out[tid];
  __syncthreads();

  const int w  = tid >> 6, l = tid & 63;
  const int lo = l & 15,  hi = l >> 4;
  float* xb = &sXp[w][0];

#define WFo(half, t) (*(const bf16x8*)&sWfrag[(half) * 4 + (t)][l][0])

  const int ntiles = (N + 15) >> 4;
  for (int tile = blockIdx.x * 8 + w; tile < ntiles; tile += gridDim.x * 8) {
    const int row = tile * 16 + lo;
    const int rowc = row < N ? row : (N - 1);
    bf16x8 sf[2];
#pragma unroll
    for (int half = 0; half < 2; ++half) {
      const int base = 32 * half + hi * 8;
      const f32x4 N0 = *(const f32x4*)&num[(size_t)rowc * 64 + base];
      const f32x4 N1 = *(const f32x4*)&num[(size_t)rowc * 64 + base + 4];
      const f32x4 D0 = *(const f32x4*)&den[(size_t)rowc * 64 + base];
      const f32x4 D1 = *(const f32x4*)&den[(size_t)rowc * 64 + base + 4];
      float t8[8];
#pragma unroll
      for (int i = 0; i < 8; ++i) {
        const float nn = (i < 4) ? N0[i] : N1[i - 4];
        const float dd = (i < 4) ? D0[i] : D1[i - 4];
        t8[i] = nn / (dd + 1e-16f);
      }
      sf[half] = mk8(cvtpk(t8[0], t8[1]), cvtpk(t8[2], t8[3]),
                     cvtpk(t8[4], t8[5]), cvtpk(t8[6], t8[7]));
    }
    f32x4 res[4];
#pragma unroll
    for (int t = 0; t < 4; ++t) {
      f32x4 acc = *(const f32x4*)&sBias[t * 16 + hi * 4];
      acc = mfma16(WFo(0, t), sf[0], acc);
      acc = mfma16(WFo(1, t), sf[1], acc);
#pragma unroll
      for (int r = 0; r < 4; ++r) res[t][r] = fmaxf(acc[r], 0.f);
    }
    LGKM0;
#pragma unroll
    for (int t = 0; t < 4; ++t)
      *(f32x4*)&xb[lo * 68 + t * 16 + hi * 4] = res[t];
    LGKM0;
#pragma unroll
    for (int ee = 0; ee < 16; ++ee) {
      const int r2 = tile * 16 + ee;
      if (r2 < N) out[(size_t)r2 * 64 + l] = xb[ee * 68 + l];
    }
  }
#undef WFo
}

extern "C" void kernel_launch(void* const* d_in, const int* in_sizes, int n_in,
                              void* d_out, int out_size, void* d_ws, size_t ws_size,
                              hipStream_t stream) {
  const float* x     = (const float*)d_in[0];
  const float* pos   = (const float*)d_in[1];
  const float* W_in  = (const float*)d_in[2];
  const float* b_in  = (const float*)d_in[3];
  const float* W_lin = (const float*)d_in[4];
  const float* W_src = (const float*)d_in[5];
  const float* W_dst = (const float*)d_in[6];
  const float* pW1   = (const float*)d_in[7];
  const float* pb1   = (const float*)d_in[8];
  const float* pW2   = (const float*)d_in[9];
  const float* pb2   = (const float*)d_in[10];
  const float* aW1   = (const float*)d_in[11];
  const float* ab1   = (const float*)d_in[12];
  const float* aW2   = (const float*)d_in[13];
  const float* ab2   = (const float*)d_in[14];
  const float* W_out = (const float*)d_in[15];
  const float* b_out = (const float*)d_in[16];
  const int*   eidx  = (const int*)d_in[17];

  const int N = in_sizes[0] / 64;
  const int E = in_sizes[17] / 2;

  char* p = (char*)d_ws;
  float* num    = (float*)p;  p += (size_t)N * 64 * 4;
  float* den    = (float*)p;  p += (size_t)N * 64 * 4;
  int*   cursor = (int*)p;    p += (size_t)N * 4;
  const size_t memset_bytes = (size_t)p - (size_t)d_ws;
  int*   bsum   = (int*)p;    p += 64 * 4;
  p = (char*)(((uintptr_t)p + 15) & ~(uintptr_t)15);
  uint4* frag   = (uint4*)p;  p += (size_t)68 * 64 * 16;
  uint32_t* sorted = (uint32_t*)p; p += (size_t)E * 4;
  unsigned short* vbf  = (unsigned short*)p; p += (size_t)N * 64 * 2;
  unsigned short* bsrc = (unsigned short*)p; p += (size_t)N * 64 * 2;
  float* bdst   = (float*)p;  p += (size_t)N * 64 * 4;

  hipMemsetAsync(d_ws, 0, memset_bytes, stream);

  combine_kernel<<<2, 256, 0, stream>>>(pW1, pb1, pW2, aW1, aW2,
                                        W_in, W_lin, W_src, W_dst, W_out, frag);

  const int HB = (E + 1023) / 1024;
  fused_prep_kernel<<<HB + 784, 256, 0, stream>>>(eidx, cursor, E,
                                                  x, b_in, ab1, frag,
                                                  vbf, bsrc, bdst, N, HB);

  const int nb = (N + SCAN_CH - 1) / SCAN_CH;
  scan_blocksum<<<nb, 256, 0, stream>>>(cursor, bsum, N);
  scan_final<<<nb, 256, 0, stream>>>(cursor, bsum, N);
  scatter_kernel<<<(E + 255) / 256, 256, 0, stream>>>(eidx, cursor, sorted, E);

  edge_mfma_kernel<<<512, 512, 0, stream>>>(pos, vbf, bsrc, bdst, pb2, ab2,
                                            frag, sorted, num, den, E);
  node_out_mfma<<<392, 512, 0, stream>>>(num, den, frag, b_out, (float*)d_out, N);
}